// Round 7
// baseline (129.291 us; speedup 1.0000x reference)
//
#include <hip/hip_runtime.h>
#include <math.h>

// B=4, T=48, W=8, H=8, C=32; d_ff=64; periods {2,3,4}. T%P==0 always.
// (1x1 + 3^4)/2 inception folded into one 81-tap conv (center tap 40).
// R21 = R20 skeleton with M=64xN=32 wave tile (LDS-read-ratio fix):
//   Model update: convs are LDS-read-throughput-bound (R20: 12 b128 reads
//   per 12 MFMA per wave per phase; 144 reads/CU/phase x ~10cyc x 27 ~= 31us
//   per conv = observed). Fix: wave = one t-site, M=64 (acc[4][2]):
//   per j = 2 wf + 4 af reads / 8 MFMA (ratio 0.75); block = 6 waves.
//   * static act window staged once (R20-verified indexing si=ts+dl*P+dq),
//     weight ring mod-4 prefetched 2 phases ahead, WAITVM(2)/1/0 ladder now
//     uniform across all 6 waves (each stages 1 piece/phase).
//   * 192 blocks/conv, 1 blk/CU (143 KB LDS), 6 waves/CU.
//   * epilogues = R19's M=64 forms (verified there).

typedef __attribute__((ext_vector_type(8))) short bf16x8;
typedef __attribute__((ext_vector_type(4))) float f32x4;
typedef unsigned short u16;

// ---- workspace offsets (u16 units) ----
#define XC 3200                 // u16 per x cell (10*10*32)
#define HC2 7168                // u16 per h1 cell (2 halves x 3584)
#define XSEG 617600             // 193 * XC   (cell 192 = zero cell)
#define ZSEG_END 639104         // + 3*7168 h1 zero-cell writes
#define W1OFF 639104            // 165888 bf16: [tap 0..80][nh(2)][1024]
#define W2OFF 804992            // 165888 bf16: [tap 0..80][kh(2)][1024]
#define H1OFF 970880            // 3 periods x 193 cells x 7168
#define H1P 1383424             // per-period stride = 193*7168
#define PREP_N 970880           // end of weight segment
#define OUT_Q 98304             // out-init float4 count (393216 fp32)
#define PREP_TOT (PREP_N + OUT_Q)

#define WAITVM(N) asm volatile("s_waitcnt vmcnt(" #N ")" ::: "memory")
#define SBAR()    asm volatile("s_barrier" ::: "memory")

__device__ __forceinline__ u16 f2bf(float f) {
    unsigned u = __float_as_uint(f);
    unsigned r = u + 0x7fffu + ((u >> 16) & 1u);
    return (u16)(r >> 16);
}
__device__ __forceinline__ float gelu_exact(float v) {
    return 0.5f * v * (1.0f + erff(v * 0.7071067811865476f));
}

// async copy of 1 KB: 64 lanes x 16 B. LDS dest = wave-uniform base + lane*16.
__device__ __forceinline__ void cp1k(const u16* g, u16* l, int lane) {
    __builtin_amdgcn_global_load_lds(
        (const __attribute__((address_space(1))) unsigned int*)(g + lane * 8),
        (__attribute__((address_space(3))) unsigned int*)(l + lane * 8),
        16, 0, 0);
}

// ---- prep: x cells (swizzled) + h1 zero cells + weights + out = x ----
__global__ __launch_bounds__(256) void prep(
    const float* __restrict__ x,
    const float* __restrict__ w1_0, const float* __restrict__ w1_1,
    const float* __restrict__ w2_0, const float* __restrict__ w2_1,
    u16* __restrict__ ws, float* __restrict__ out) {
    int i = blockIdx.x * 256 + threadIdx.x;
    if (i < XSEG) {
        int cellidx = i / XC; int inner = i - cellidx * XC;
        int cellpos = inner >> 5; int low = inner & 31;
        int sc = low >> 3, jj = low & 7;
        int c = ((sc ^ (cellpos & 3)) << 3) + jj;
        int wp = cellpos / 10, hp = cellpos - (cellpos / 10) * 10;
        float v = 0.f;
        if (cellidx < 192 && wp >= 1 && wp <= 8 && hp >= 1 && hp <= 8)
            v = x[(cellidx * 64 + (wp - 1) * 8 + (hp - 1)) * 32 + c];
        ws[i] = f2bf(v);
    } else if (i < ZSEG_END) {
        int j = i - XSEG;                 // 3 h1 zero cells (full 7168 each)
        int per = j / 7168; int off = j - per * 7168;
        ws[H1OFF + per * H1P + 192 * 7168 + off] = 0;
    } else if (i < W2OFF) {
        // w1: [tap][nh][chunkh(128)*8+jj], chunkh = (quad*2+nq)*16+m
        int j = i - W1OFF;
        int tap = j >> 11; int r = j & 2047;
        int nh = r >> 10; int rr = r & 1023;
        int chunkh = rr >> 3, jj = rr & 7;
        int m = chunkh & 15, nq = (chunkh >> 4) & 1, quad = chunkh >> 5;
        int o = nh * 32 + nq * 16 + m, c = quad * 8 + jj;
        float v = 0.5f * w1_1[(o * 32 + c) * 81 + tap];
        if (tap == 40) v += 0.5f * w1_0[o * 32 + c];
        ws[i] = f2bf(v);
    } else if (i < PREP_N) {
        // w2: [tap][kh][chunkh(128)*8+jj], chunkh = (quad*2+nt)*16+m
        int j = i - W2OFF;
        int tap = j >> 11; int r = j & 2047;
        int kh = r >> 10; int rr = r & 1023;
        int chunkh = rr >> 3, jj = rr & 7;
        int m = chunkh & 15, nt = (chunkh >> 4) & 1, quad = chunkh >> 5;
        int o = nt * 16 + m, c = kh * 32 + quad * 8 + jj;
        float v = 0.5f * w2_1[(o * 64 + c) * 81 + tap];
        if (tap == 40) v += 0.5f * w2_0[o * 64 + c];
        ws[i] = f2bf(v);
    } else if (i < PREP_TOT) {
        int j = i - PREP_N;
        ((float4*)out)[j] = ((const float4*)x)[j];
    }
}

// ---- conv1 (C32 -> 32 of C64, nh half), 6 t-sites per block + GELU.
// 6 waves (wave = t-site), M=64 x N=32, acc[4][2].
// Static act window; weight-ring-only main loop. ----
template<int P>
__device__ __forceinline__ void conv1_body(
    const u16* __restrict__ xs, const u16* __restrict__ w1b,
    u16* __restrict__ h1, int tpp, int bb, int nh,
    u16* __restrict__ s_a, u16* __restrict__ s_w) {
    constexpr int HB = (P == 2) ? 0 : (P == 3) ? H1P : 2 * H1P;
    constexpr int L = 48 / P;
    constexpr int EXT = P + 1;
    constexpr int NW = 6 + 2 * EXT;      // window cells (12/14/16)
    constexpr int ZS = NW;               // zero slot index
    constexpr int NP = (NW + 1) * 7;     // staged pieces

    int tid = threadIdx.x;
    int lane = tid & 63, wv = tid >> 6;  // 6 waves; wv = t-site
    int m = lane & 15, quad = lane >> 4;
    int t0 = tpp * 6, t = t0 + wv;
    int l = t / P, q = t - l * P;

    int sp[4];
#pragma unroll
    for (int mtl = 0; mtl < 4; ++mtl) {
        int pos = mtl * 16 + m;
        sp[mtl] = (pos >> 3) * 10 + (pos & 7);
    }

    f32x4 acc[4][2];
#pragma unroll
    for (int mtl = 0; mtl < 4; ++mtl)
#pragma unroll
        for (int nq = 0; nq < 2; ++nq) acc[mtl][nq] = f32x4{0.f, 0.f, 0.f, 0.f};

    // prologue: stage act window once (slot si <-> t' = t0-EXT+si; ZS = zero)
    for (int p = wv; p < NP; p += 6) {
        int si = p / 7, pc = p - si * 7;
        int tt = t0 - EXT + si;
        int cell = (si == ZS) ? 192
                 : (((unsigned)tt < 48u) ? bb * 48 + tt : 192);
        cp1k(xs + cell * XC + pc * 512, s_a + si * 3584 + pc * 512, lane);
    }
    // W(0), W(1): every wave carries 1 piece per chunk (tap wv>>1, part wv&1)
    cp1k(w1b + (0 * 3 + (wv >> 1)) * 2048 + nh * 1024 + (wv & 1) * 512,
         s_w + 0 * 3072 + wv * 512, lane);
    cp1k(w1b + (1 * 3 + (wv >> 1)) * 2048 + nh * 1024 + (wv & 1) * 512,
         s_w + 1 * 3072 + wv * 512, lane);
    WAITVM(1);                           // acts + W0 done, W1 in flight
    SBAR();

#pragma unroll 1
    for (int cg = 0; cg < 27; ++cg) {
        // issue W(cg+2) into slot (cg+2)&3 (last read at cg-2, fenced by
        // SBAR@cg-1). Per-wave queue: [W(cg),W(cg+1),W(cg+2)] -> 2; tail 1,0.
        if (cg < 25)
            cp1k(w1b + ((cg + 2) * 3 + (wv >> 1)) * 2048 + nh * 1024 +
                     (wv & 1) * 512,
                 s_w + ((cg + 2) & 3) * 3072 + wv * 512, lane);
        if (cg < 25)       { WAITVM(2); }
        else if (cg == 25) { WAITVM(1); }
        else               { WAITVM(0); }
        SBAR();

        int g2 = cg / 3, dw = cg - g2 * 3;
        int dl = g2 / 3, dq = g2 - dl * 3;
        int lq = l + dl - 1, qq = q + dq - 1;
        bool valid = ((unsigned)lq < (unsigned)L) &&
                     ((unsigned)qq < (unsigned)P);
        int si = valid ? (wv + dl * P + dq) : ZS;   // t'-(t0-EXT), in [0,NW)
        const u16* ba = s_a + si * 3584;
        const u16* bw = s_w + (cg & 3) * 3072;
#pragma unroll
        for (int j = 0; j < 3; ++j) {
            const u16* tw = bw + j * 1024;
            bf16x8 wf0 = *(const bf16x8*)(tw + (((quad * 2 + 0) * 16 + m) << 3));
            bf16x8 wf1 = *(const bf16x8*)(tw + (((quad * 2 + 1) * 16 + m) << 3));
#pragma unroll
            for (int mtl = 0; mtl < 4; ++mtl) {
                int cellpos = sp[mtl] + dw * 10 + j;
                bf16x8 af = *(const bf16x8*)(ba + cellpos * 32 +
                                             ((quad ^ (cellpos & 3)) << 3));
                acc[mtl][0] = __builtin_amdgcn_mfma_f32_16x16x32_bf16(
                    af, wf0, acc[mtl][0], 0, 0, 0);
                acc[mtl][1] = __builtin_amdgcn_mfma_f32_16x16x32_bf16(
                    af, wf1, acc[mtl][1], 0, 0, 0);
            }
        }
    }

    // epilogue: GELU -> bf16 -> swizzled half-cell interior
    u16* hh = h1 + HB + (bb * 48 + t) * HC2 + nh * 3584;
#pragma unroll
    for (int mtl = 0; mtl < 4; ++mtl)
#pragma unroll
        for (int r = 0; r < 4; ++r) {
            int pos = mtl * 16 + quad * 4 + r;
            int cellpos = ((pos >> 3) + 1) * 10 + (pos & 7) + 1;
#pragma unroll
            for (int nq = 0; nq < 2; ++nq) {
                int ol = nq * 16 + m;
                hh[cellpos * 32 + (((ol >> 3) ^ (cellpos & 3)) << 3) + (ol & 7)] =
                    f2bf(gelu_exact(acc[mtl][nq][r]));
            }
        }
    // zero the 36 border cellpos of all 6 t half-cells (unique writer)
#pragma unroll
    for (int it = 0; it < 9; ++it) {
        int k = it * 384 + tid;                    // 9*384 = 3456 exactly
        int tc = k / 576; int rr = k - tc * 576;
        int bp = rr >> 4, u = rr & 15;
        int cp;
        if (bp < 10) cp = bp;
        else if (bp < 20) cp = 90 + (bp - 10);
        else if (bp < 28) cp = (bp - 19) * 10;
        else cp = (bp - 27) * 10 + 9;
        unsigned int* h32 = (unsigned int*)(h1 + HB +
            (bb * 48 + t0 + tc) * HC2 + nh * 3584);
        h32[cp * 16 + u] = 0;
    }
}

__global__ __launch_bounds__(384) void conv1_k(
    const u16* __restrict__ ws_x, const u16* __restrict__ ws_w1,
    u16* __restrict__ ws_h1) {
    __shared__ __align__(16) u16 s_a[17 * 3584];   // 119 KB act window
    __shared__ __align__(16) u16 s_w[4 * 3072];    // 24 KB weight ring
    int g = blockIdx.x;
    int jid = (g & 7) * 24 + (g >> 3);             // XCD-chunked, 192 = 8*24
    int per = jid / 64; int rem = jid - per * 64;
    int bb = rem / 16; int r2 = rem - bb * 16;
    int tpp = r2 >> 1, nh = r2 & 1;
    if (per == 0)      conv1_body<2>(ws_x, ws_w1, ws_h1, tpp, bb, nh, s_a, s_w);
    else if (per == 1) conv1_body<3>(ws_x, ws_w1, ws_h1, tpp, bb, nh, s_a, s_w);
    else               conv1_body<4>(ws_x, ws_w1, ws_h1, tpp, bb, nh, s_a, s_w);
}

// ---- conv2 (32 of C64 -> C32 partial, kh half), 6 t-sites per block.
// Same structure; epilogue atomicAdds acc/3 into out (pre-filled with x). ----
template<int P>
__device__ __forceinline__ void conv2_body(
    const u16* __restrict__ h1, const u16* __restrict__ w2b,
    float* __restrict__ out, int tpp, int bb, int kh,
    u16* __restrict__ s_a, u16* __restrict__ s_w) {
    constexpr int HB = (P == 2) ? 0 : (P == 3) ? H1P : 2 * H1P;
    constexpr int L = 48 / P;
    constexpr int EXT = P + 1;
    constexpr int NW = 6 + 2 * EXT;
    constexpr int ZS = NW;
    constexpr int NP = (NW + 1) * 7;

    int tid = threadIdx.x;
    int lane = tid & 63, wv = tid >> 6;
    int m = lane & 15, quad = lane >> 4;
    int t0 = tpp * 6, t = t0 + wv;
    int l = t / P, q = t - l * P;
    const u16* hb = h1 + HB;

    int sp[4];
#pragma unroll
    for (int mtl = 0; mtl < 4; ++mtl) {
        int pos = mtl * 16 + m;
        sp[mtl] = (pos >> 3) * 10 + (pos & 7);
    }

    f32x4 acc[4][2];
#pragma unroll
    for (int mtl = 0; mtl < 4; ++mtl)
#pragma unroll
        for (int nt = 0; nt < 2; ++nt) acc[mtl][nt] = f32x4{0.f, 0.f, 0.f, 0.f};

    for (int p = wv; p < NP; p += 6) {
        int si = p / 7, pc = p - si * 7;
        int tt = t0 - EXT + si;
        int cell = (si == ZS) ? 192
                 : (((unsigned)tt < 48u) ? bb * 48 + tt : 192);
        cp1k(hb + cell * HC2 + kh * 3584 + pc * 512,
             s_a + si * 3584 + pc * 512, lane);
    }
    cp1k(w2b + (0 * 3 + (wv >> 1)) * 2048 + kh * 1024 + (wv & 1) * 512,
         s_w + 0 * 3072 + wv * 512, lane);
    cp1k(w2b + (1 * 3 + (wv >> 1)) * 2048 + kh * 1024 + (wv & 1) * 512,
         s_w + 1 * 3072 + wv * 512, lane);
    WAITVM(1);
    SBAR();

#pragma unroll 1
    for (int cg = 0; cg < 27; ++cg) {
        if (cg < 25)
            cp1k(w2b + ((cg + 2) * 3 + (wv >> 1)) * 2048 + kh * 1024 +
                     (wv & 1) * 512,
                 s_w + ((cg + 2) & 3) * 3072 + wv * 512, lane);
        if (cg < 25)       { WAITVM(2); }
        else if (cg == 25) { WAITVM(1); }
        else               { WAITVM(0); }
        SBAR();

        int g2 = cg / 3, dw = cg - g2 * 3;
        int dl = g2 / 3, dq = g2 - dl * 3;
        int lq = l + dl - 1, qq = q + dq - 1;
        bool valid = ((unsigned)lq < (unsigned)L) &&
                     ((unsigned)qq < (unsigned)P);
        int si = valid ? (wv + dl * P + dq) : ZS;
        const u16* ba = s_a + si * 3584;
        const u16* bw = s_w + (cg & 3) * 3072;
#pragma unroll
        for (int j = 0; j < 3; ++j) {
            const u16* tw = bw + j * 1024;
            bf16x8 wf0 = *(const bf16x8*)(tw + (((quad * 2 + 0) * 16 + m) << 3));
            bf16x8 wf1 = *(const bf16x8*)(tw + (((quad * 2 + 1) * 16 + m) << 3));
#pragma unroll
            for (int mtl = 0; mtl < 4; ++mtl) {
                int cellpos = sp[mtl] + dw * 10 + j;
                bf16x8 af = *(const bf16x8*)(ba + cellpos * 32 +
                                             ((quad ^ (cellpos & 3)) << 3));
                acc[mtl][0] = __builtin_amdgcn_mfma_f32_16x16x32_bf16(
                    af, wf0, acc[mtl][0], 0, 0, 0);
                acc[mtl][1] = __builtin_amdgcn_mfma_f32_16x16x32_bf16(
                    af, wf1, acc[mtl][1], 0, 0, 0);
            }
        }
    }

    // epilogue: out += acc/3 (softmax(ones) weights); out pre-filled with x
    float* orow = out + (bb * 48 + t) * 2048;
    const float s = 1.0f / 3.0f;
#pragma unroll
    for (int mtl = 0; mtl < 4; ++mtl)
#pragma unroll
        for (int nt = 0; nt < 2; ++nt)
#pragma unroll
            for (int r = 0; r < 4; ++r) {
                int pos = mtl * 16 + quad * 4 + r;
                atomicAdd(&orow[pos * 32 + nt * 16 + m], acc[mtl][nt][r] * s);
            }
}

__global__ __launch_bounds__(384) void conv2_k(
    const u16* __restrict__ ws_h1, const u16* __restrict__ ws_w2,
    float* __restrict__ out) {
    __shared__ __align__(16) u16 s_a[17 * 3584];   // 119 KB act window
    __shared__ __align__(16) u16 s_w[4 * 3072];    // 24 KB weight ring
    int g = blockIdx.x;
    int jid = (g & 7) * 24 + (g >> 3);             // same XCD mapping as conv1
    int per = jid / 64; int rem = jid - per * 64;
    int bb = rem / 16; int r2 = rem - bb * 16;
    int tpp = r2 >> 1, kh = r2 & 1;
    if (per == 0)      conv2_body<2>(ws_h1, ws_w2, out, tpp, bb, kh, s_a, s_w);
    else if (per == 1) conv2_body<3>(ws_h1, ws_w2, out, tpp, bb, kh, s_a, s_w);
    else               conv2_body<4>(ws_h1, ws_w2, out, tpp, bb, kh, s_a, s_w);
}

extern "C" void kernel_launch(void* const* d_in, const int* in_sizes, int n_in,
                              void* d_out, int out_size, void* d_ws, size_t ws_size,
                              hipStream_t stream) {
    const float* x    = (const float*)d_in[0];
    const float* w1_0 = (const float*)d_in[1];
    const float* w1_1 = (const float*)d_in[2];
    const float* w2_0 = (const float*)d_in[3];
    const float* w2_1 = (const float*)d_in[4];
    float* out = (float*)d_out;

    u16* ws = (u16*)d_ws;
    u16* ws_x  = ws;                 // 193 cells (192 real + zero)
    u16* ws_w1 = ws + W1OFF;
    u16* ws_w2 = ws + W2OFF;
    u16* ws_h1 = ws + H1OFF;         // 3 x 193 cells x 7168

    prep<<<(PREP_TOT + 255) / 256, 256, 0, stream>>>(
        x, w1_0, w1_1, w2_0, w2_1, ws, out);
    conv1_k<<<192, 384, 0, stream>>>(ws_x, ws_w1, ws_h1);
    conv2_k<<<192, 384, 0, stream>>>(ws_h1, ws_w2, out);
}

// Round 8
// 116.103 us; speedup vs baseline: 1.1136x; 1.1136x over previous
//
#include <hip/hip_runtime.h>
#include <math.h>

// B=4, T=48, W=8, H=8, C=32; d_ff=64; periods {2,3,4}. T%P==0 always.
// (1x1 + 3^4)/2 inception folded into one 81-tap conv (center tap 40).
// R22 = R20 (best: 12-wave blocks, M=32 wave tile, static act window,
// grid 192) with the weight stream re-granularized to 9-tap super-chunks:
//   * R21 falsified LDS-read-bound theory (fewer reads, fewer waves ->
//     slower). At 12 w/CU the residual is per-phase barrier skew (~1300cyc
//     x 27). Cut phases 27 -> 9: super-chunk = one (dl,dq) group = 9 taps
//     (18 KB), mod-2 ring (36 KB; LDS total 155 KB, 1 blk/CU, 12 w/CU).
//   * Phase protocol: issue S(g+1) at phase START (safe: previous phase's
//     trailing SBAR guarantees all waves finished compute(g-1), the last
//     reader of slot (g+1)&1); 36 MFMA/wave; WAITVM(0)+SBAR at END. The
//     vmcnt(0) targets a load issued a full phase (~2500cyc) earlier ->
//     pre-satisfied. Barriers/conv: 28 -> 10.
//   * si (act cell) now constant per phase -> less per-phase address VALU.

typedef __attribute__((ext_vector_type(8))) short bf16x8;
typedef __attribute__((ext_vector_type(4))) float f32x4;
typedef unsigned short u16;

// ---- workspace offsets (u16 units) ----
#define XC 3200                 // u16 per x cell (10*10*32)
#define HC2 7168                // u16 per h1 cell (2 halves x 3584)
#define XSEG 617600             // 193 * XC   (cell 192 = zero cell)
#define ZSEG_END 639104         // + 3*7168 h1 zero-cell writes
#define W1OFF 639104            // 165888 bf16: [tap 0..80][nh(2)][1024]
#define W2OFF 804992            // 165888 bf16: [tap 0..80][kh(2)][1024]
#define H1OFF 970880            // 3 periods x 193 cells x 7168
#define H1P 1383424             // per-period stride = 193*7168
#define PREP_N 970880           // end of weight segment
#define OUT_Q 98304             // out-init float4 count (393216 fp32)
#define PREP_TOT (PREP_N + OUT_Q)

#define WAITVM(N) asm volatile("s_waitcnt vmcnt(" #N ")" ::: "memory")
#define SBAR()    asm volatile("s_barrier" ::: "memory")

__device__ __forceinline__ u16 f2bf(float f) {
    unsigned u = __float_as_uint(f);
    unsigned r = u + 0x7fffu + ((u >> 16) & 1u);
    return (u16)(r >> 16);
}
__device__ __forceinline__ float gelu_exact(float v) {
    return 0.5f * v * (1.0f + erff(v * 0.7071067811865476f));
}

// async copy of 1 KB: 64 lanes x 16 B. LDS dest = wave-uniform base + lane*16.
__device__ __forceinline__ void cp1k(const u16* g, u16* l, int lane) {
    __builtin_amdgcn_global_load_lds(
        (const __attribute__((address_space(1))) unsigned int*)(g + lane * 8),
        (__attribute__((address_space(3))) unsigned int*)(l + lane * 8),
        16, 0, 0);
}

// ---- prep: x cells (swizzled) + h1 zero cells + weights + out = x ----
__global__ __launch_bounds__(256) void prep(
    const float* __restrict__ x,
    const float* __restrict__ w1_0, const float* __restrict__ w1_1,
    const float* __restrict__ w2_0, const float* __restrict__ w2_1,
    u16* __restrict__ ws, float* __restrict__ out) {
    int i = blockIdx.x * 256 + threadIdx.x;
    if (i < XSEG) {
        int cellidx = i / XC; int inner = i - cellidx * XC;
        int cellpos = inner >> 5; int low = inner & 31;
        int sc = low >> 3, jj = low & 7;
        int c = ((sc ^ (cellpos & 3)) << 3) + jj;
        int wp = cellpos / 10, hp = cellpos - (cellpos / 10) * 10;
        float v = 0.f;
        if (cellidx < 192 && wp >= 1 && wp <= 8 && hp >= 1 && hp <= 8)
            v = x[(cellidx * 64 + (wp - 1) * 8 + (hp - 1)) * 32 + c];
        ws[i] = f2bf(v);
    } else if (i < ZSEG_END) {
        int j = i - XSEG;                 // 3 h1 zero cells (full 7168 each)
        int per = j / 7168; int off = j - per * 7168;
        ws[H1OFF + per * H1P + 192 * 7168 + off] = 0;
    } else if (i < W2OFF) {
        // w1: [tap][nh][chunkh(128)*8+jj], chunkh = (quad*2+nq)*16+m
        int j = i - W1OFF;
        int tap = j >> 11; int r = j & 2047;
        int nh = r >> 10; int rr = r & 1023;
        int chunkh = rr >> 3, jj = rr & 7;
        int m = chunkh & 15, nq = (chunkh >> 4) & 1, quad = chunkh >> 5;
        int o = nh * 32 + nq * 16 + m, c = quad * 8 + jj;
        float v = 0.5f * w1_1[(o * 32 + c) * 81 + tap];
        if (tap == 40) v += 0.5f * w1_0[o * 32 + c];
        ws[i] = f2bf(v);
    } else if (i < PREP_N) {
        // w2: [tap][kh][chunkh(128)*8+jj], chunkh = (quad*2+nt)*16+m
        int j = i - W2OFF;
        int tap = j >> 11; int r = j & 2047;
        int kh = r >> 10; int rr = r & 1023;
        int chunkh = rr >> 3, jj = rr & 7;
        int m = chunkh & 15, nt = (chunkh >> 4) & 1, quad = chunkh >> 5;
        int o = nt * 16 + m, c = kh * 32 + quad * 8 + jj;
        float v = 0.5f * w2_1[(o * 64 + c) * 81 + tap];
        if (tap == 40) v += 0.5f * w2_0[o * 64 + c];
        ws[i] = f2bf(v);
    } else if (i < PREP_TOT) {
        int j = i - PREP_N;
        ((float4*)out)[j] = ((const float4*)x)[j];
    }
}

// ---- conv1 (C32 -> 32 of C64, nh half), 6 t-sites per block + GELU.
// 12 waves = (ts in 6, mh in 2), M=32 x N=32 per wave, acc[2][2].
// Static act window; 9-phase weight super-chunk ring. ----
template<int P>
__device__ __forceinline__ void conv1_body(
    const u16* __restrict__ xs, const u16* __restrict__ w1b,
    u16* __restrict__ h1, int tpp, int bb, int nh,
    u16* __restrict__ s_a, u16* __restrict__ s_w) {
    constexpr int HB = (P == 2) ? 0 : (P == 3) ? H1P : 2 * H1P;
    constexpr int L = 48 / P;
    constexpr int EXT = P + 1;
    constexpr int NW = 6 + 2 * EXT;      // window cells (12/14/16)
    constexpr int ZS = NW;               // zero slot index
    constexpr int NP = (NW + 1) * 7;     // staged pieces

    int tid = threadIdx.x;
    int lane = tid & 63, wv = tid >> 6;  // 12 waves
    int m = lane & 15, quad = lane >> 4;
    int ts = wv >> 1, mh = wv & 1;
    int t0 = tpp * 6, t = t0 + ts;
    int l = t / P, q = t - l * P;

    int sp[2];
#pragma unroll
    for (int mtl = 0; mtl < 2; ++mtl) {
        int pos = (mh * 2 + mtl) * 16 + m;
        sp[mtl] = (pos >> 3) * 10 + (pos & 7);
    }

    f32x4 acc[2][2];
#pragma unroll
    for (int mtl = 0; mtl < 2; ++mtl)
#pragma unroll
        for (int nq = 0; nq < 2; ++nq) acc[mtl][nq] = f32x4{0.f, 0.f, 0.f, 0.f};

    // super-chunk sg = taps 9sg..9sg+8 (one (dl,dq) group), nh half:
    // 18 pieces of 512, 2/wave (k>=18 dup piece 17: same src+dst, benign)
    auto stageS = [&](int sg) {
        const u16* src = w1b + nh * 1024;
        u16* dst = s_w + (sg & 1) * 9216;
#pragma unroll
        for (int i = 0; i < 2; ++i) {
            int k = wv * 2 + i; if (k >= 18) k = 17;
            cp1k(src + (sg * 9 + (k >> 1)) * 2048 + (k & 1) * 512,
                 dst + k * 512, lane);
        }
    };

    // prologue: stage act window once (slot si <-> t' = t0-EXT+si; ZS = zero)
    for (int p = wv; p < NP; p += 12) {
        int si = p / 7, pc = p - si * 7;
        int tt = t0 - EXT + si;
        int cell = (si == ZS) ? 192
                 : (((unsigned)tt < 48u) ? bb * 48 + tt : 192);
        cp1k(xs + cell * XC + pc * 512, s_a + si * 3584 + pc * 512, lane);
    }
    stageS(0);
    WAITVM(0); SBAR();

#pragma unroll 1
    for (int g = 0; g < 9; ++g) {
        // issue S(g+1) into slot (g+1)&1 (last read by compute(g-1); the
        // trailing SBAR of phase g-1 guarantees all waves finished it).
        if (g < 8) stageS(g + 1);

        int dl = g / 3, dq = g - dl * 3;
        int lq = l + dl - 1, qq = q + dq - 1;
        bool valid = ((unsigned)lq < (unsigned)L) &&
                     ((unsigned)qq < (unsigned)P);
        int si = valid ? (ts + dl * P + dq) : ZS;   // constant this phase
        const u16* ba = s_a + si * 3584;
        const u16* bw = s_w + (g & 1) * 9216;
#pragma unroll
        for (int dw = 0; dw < 3; ++dw)
#pragma unroll
            for (int j = 0; j < 3; ++j) {
                const u16* tw = bw + (dw * 3 + j) * 1024;
                bf16x8 wf0 = *(const bf16x8*)(tw +
                    (((quad * 2 + 0) * 16 + m) << 3));
                bf16x8 wf1 = *(const bf16x8*)(tw +
                    (((quad * 2 + 1) * 16 + m) << 3));
#pragma unroll
                for (int mtl = 0; mtl < 2; ++mtl) {
                    int cellpos = sp[mtl] + dw * 10 + j;
                    bf16x8 af = *(const bf16x8*)(ba + cellpos * 32 +
                                                 ((quad ^ (cellpos & 3)) << 3));
                    acc[mtl][0] = __builtin_amdgcn_mfma_f32_16x16x32_bf16(
                        af, wf0, acc[mtl][0], 0, 0, 0);
                    acc[mtl][1] = __builtin_amdgcn_mfma_f32_16x16x32_bf16(
                        af, wf1, acc[mtl][1], 0, 0, 0);
                }
            }
        // S(g+1) issued a full phase before its WAITVM in phase g+1 would
        // need it; this wait is on S(g+1) only (everything older is done).
        if (g < 8) { WAITVM(0); SBAR(); }
    }

    // epilogue: GELU -> bf16 -> swizzled half-cell interior
    u16* hh = h1 + HB + (bb * 48 + t) * HC2 + nh * 3584;
#pragma unroll
    for (int mtl = 0; mtl < 2; ++mtl)
#pragma unroll
        for (int r = 0; r < 4; ++r) {
            int pos = (mh * 2 + mtl) * 16 + quad * 4 + r;
            int cellpos = ((pos >> 3) + 1) * 10 + (pos & 7) + 1;
#pragma unroll
            for (int nq = 0; nq < 2; ++nq) {
                int ol = nq * 16 + m;
                hh[cellpos * 32 + (((ol >> 3) ^ (cellpos & 3)) << 3) + (ol & 7)] =
                    f2bf(gelu_exact(acc[mtl][nq][r]));
            }
        }
    // zero the 36 border cellpos of all 6 t half-cells (unique writer)
#pragma unroll
    for (int it = 0; it < 5; ++it) {
        int k = it * 768 + tid;                    // 6*576 = 3456 entries
        if (k < 3456) {
            int tc = k / 576; int rr = k - tc * 576;
            int bp = rr >> 4, u = rr & 15;
            int cp;
            if (bp < 10) cp = bp;
            else if (bp < 20) cp = 90 + (bp - 10);
            else if (bp < 28) cp = (bp - 19) * 10;
            else cp = (bp - 27) * 10 + 9;
            unsigned int* h32 = (unsigned int*)(h1 + HB +
                (bb * 48 + t0 + tc) * HC2 + nh * 3584);
            h32[cp * 16 + u] = 0;
        }
    }
}

__global__ __launch_bounds__(768) void conv1_k(
    const u16* __restrict__ ws_x, const u16* __restrict__ ws_w1,
    u16* __restrict__ ws_h1) {
    __shared__ __align__(16) u16 s_a[17 * 3584];   // 119 KB act window
    __shared__ __align__(16) u16 s_w[2 * 9216];    // 36 KB super-chunk ring
    int g = blockIdx.x;
    int jid = (g & 7) * 24 + (g >> 3);             // XCD-chunked, 192 = 8*24
    int per = jid / 64; int rem = jid - per * 64;
    int bb = rem / 16; int r2 = rem - bb * 16;
    int tpp = r2 >> 1, nh = r2 & 1;
    if (per == 0)      conv1_body<2>(ws_x, ws_w1, ws_h1, tpp, bb, nh, s_a, s_w);
    else if (per == 1) conv1_body<3>(ws_x, ws_w1, ws_h1, tpp, bb, nh, s_a, s_w);
    else               conv1_body<4>(ws_x, ws_w1, ws_h1, tpp, bb, nh, s_a, s_w);
}

// ---- conv2 (32 of C64 -> C32 partial, kh half), 6 t-sites per block.
// Same 9-phase structure; epilogue atomicAdds acc/3 into out. ----
template<int P>
__device__ __forceinline__ void conv2_body(
    const u16* __restrict__ h1, const u16* __restrict__ w2b,
    float* __restrict__ out, int tpp, int bb, int kh,
    u16* __restrict__ s_a, u16* __restrict__ s_w) {
    constexpr int HB = (P == 2) ? 0 : (P == 3) ? H1P : 2 * H1P;
    constexpr int L = 48 / P;
    constexpr int EXT = P + 1;
    constexpr int NW = 6 + 2 * EXT;
    constexpr int ZS = NW;
    constexpr int NP = (NW + 1) * 7;

    int tid = threadIdx.x;
    int lane = tid & 63, wv = tid >> 6;
    int m = lane & 15, quad = lane >> 4;
    int ts = wv >> 1, mh = wv & 1;
    int t0 = tpp * 6, t = t0 + ts;
    int l = t / P, q = t - l * P;
    const u16* hb = h1 + HB;

    int sp[2];
#pragma unroll
    for (int mtl = 0; mtl < 2; ++mtl) {
        int pos = (mh * 2 + mtl) * 16 + m;
        sp[mtl] = (pos >> 3) * 10 + (pos & 7);
    }

    f32x4 acc[2][2];
#pragma unroll
    for (int mtl = 0; mtl < 2; ++mtl)
#pragma unroll
        for (int nt = 0; nt < 2; ++nt) acc[mtl][nt] = f32x4{0.f, 0.f, 0.f, 0.f};

    auto stageS = [&](int sg) {
        const u16* src = w2b + kh * 1024;
        u16* dst = s_w + (sg & 1) * 9216;
#pragma unroll
        for (int i = 0; i < 2; ++i) {
            int k = wv * 2 + i; if (k >= 18) k = 17;
            cp1k(src + (sg * 9 + (k >> 1)) * 2048 + (k & 1) * 512,
                 dst + k * 512, lane);
        }
    };

    for (int p = wv; p < NP; p += 12) {
        int si = p / 7, pc = p - si * 7;
        int tt = t0 - EXT + si;
        int cell = (si == ZS) ? 192
                 : (((unsigned)tt < 48u) ? bb * 48 + tt : 192);
        cp1k(hb + cell * HC2 + kh * 3584 + pc * 512,
             s_a + si * 3584 + pc * 512, lane);
    }
    stageS(0);
    WAITVM(0); SBAR();

#pragma unroll 1
    for (int g = 0; g < 9; ++g) {
        if (g < 8) stageS(g + 1);

        int dl = g / 3, dq = g - dl * 3;
        int lq = l + dl - 1, qq = q + dq - 1;
        bool valid = ((unsigned)lq < (unsigned)L) &&
                     ((unsigned)qq < (unsigned)P);
        int si = valid ? (ts + dl * P + dq) : ZS;
        const u16* ba = s_a + si * 3584;
        const u16* bw = s_w + (g & 1) * 9216;
#pragma unroll
        for (int dw = 0; dw < 3; ++dw)
#pragma unroll
            for (int j = 0; j < 3; ++j) {
                const u16* tw = bw + (dw * 3 + j) * 1024;
                bf16x8 wf0 = *(const bf16x8*)(tw +
                    (((quad * 2 + 0) * 16 + m) << 3));
                bf16x8 wf1 = *(const bf16x8*)(tw +
                    (((quad * 2 + 1) * 16 + m) << 3));
#pragma unroll
                for (int mtl = 0; mtl < 2; ++mtl) {
                    int cellpos = sp[mtl] + dw * 10 + j;
                    bf16x8 af = *(const bf16x8*)(ba + cellpos * 32 +
                                                 ((quad ^ (cellpos & 3)) << 3));
                    acc[mtl][0] = __builtin_amdgcn_mfma_f32_16x16x32_bf16(
                        af, wf0, acc[mtl][0], 0, 0, 0);
                    acc[mtl][1] = __builtin_amdgcn_mfma_f32_16x16x32_bf16(
                        af, wf1, acc[mtl][1], 0, 0, 0);
                }
            }
        if (g < 8) { WAITVM(0); SBAR(); }
    }

    // epilogue: out += acc/3 (softmax(ones) weights); out pre-filled with x
    float* orow = out + (bb * 48 + t) * 2048;
    const float s = 1.0f / 3.0f;
#pragma unroll
    for (int mtl = 0; mtl < 2; ++mtl)
#pragma unroll
        for (int nt = 0; nt < 2; ++nt)
#pragma unroll
            for (int r = 0; r < 4; ++r) {
                int pos = (mh * 2 + mtl) * 16 + quad * 4 + r;
                atomicAdd(&orow[pos * 32 + nt * 16 + m], acc[mtl][nt][r] * s);
            }
}

__global__ __launch_bounds__(768) void conv2_k(
    const u16* __restrict__ ws_h1, const u16* __restrict__ ws_w2,
    float* __restrict__ out) {
    __shared__ __align__(16) u16 s_a[17 * 3584];   // 119 KB act window
    __shared__ __align__(16) u16 s_w[2 * 9216];    // 36 KB super-chunk ring
    int g = blockIdx.x;
    int jid = (g & 7) * 24 + (g >> 3);             // same XCD mapping as conv1
    int per = jid / 64; int rem = jid - per * 64;
    int bb = rem / 16; int r2 = rem - bb * 16;
    int tpp = r2 >> 1, kh = r2 & 1;
    if (per == 0)      conv2_body<2>(ws_h1, ws_w2, out, tpp, bb, kh, s_a, s_w);
    else if (per == 1) conv2_body<3>(ws_h1, ws_w2, out, tpp, bb, kh, s_a, s_w);
    else               conv2_body<4>(ws_h1, ws_w2, out, tpp, bb, kh, s_a, s_w);
}

extern "C" void kernel_launch(void* const* d_in, const int* in_sizes, int n_in,
                              void* d_out, int out_size, void* d_ws, size_t ws_size,
                              hipStream_t stream) {
    const float* x    = (const float*)d_in[0];
    const float* w1_0 = (const float*)d_in[1];
    const float* w1_1 = (const float*)d_in[2];
    const float* w2_0 = (const float*)d_in[3];
    const float* w2_1 = (const float*)d_in[4];
    float* out = (float*)d_out;

    u16* ws = (u16*)d_ws;
    u16* ws_x  = ws;                 // 193 cells (192 real + zero)
    u16* ws_w1 = ws + W1OFF;
    u16* ws_w2 = ws + W2OFF;
    u16* ws_h1 = ws + H1OFF;         // 3 x 193 cells x 7168

    prep<<<(PREP_TOT + 255) / 256, 256, 0, stream>>>(
        x, w1_0, w1_1, w2_0, w2_1, ws, out);
    conv1_k<<<192, 768, 0, stream>>>(ws_x, ws_w1, ws_h1);
    conv2_k<<<192, 768, 0, stream>>>(ws_h1, ws_w2, out);
}

// Round 9
// 109.344 us; speedup vs baseline: 1.1824x; 1.0618x over previous
//
#include <hip/hip_runtime.h>
#include <math.h>

// B=4, T=48, W=8, H=8, C=32; d_ff=64; periods {2,3,4}. T%P==0 always.
// (1x1 + 3^4)/2 inception folded into one 81-tap conv (center tap 40).
// R23 = R22 (best: 12-wave blocks, M=32 wave tile, static act window,
// 9-phase weight super-chunk ring, grid 192) + SKIP ZERO PHASES:
//   * ~27% of (site,dl,dq) phases hit an out-of-bounds neighbor -> were
//     staged zero cells + full 36 reads + 36 MFMA of exact zeros. valid is
//     wave-uniform -> wrap compute in uniform branch, skip it; skip staging
//     of out-of-range window slots; delete the zero slot (LDS 155->148 KB).
//   * Barrier/ring protocol unchanged: all waves stage weights and hit all
//     barriers; skipping wave's WAITVM(0) overlaps others' compute.
//   * Skipped MFMAs contributed exact zeros -> bit-identical output.

typedef __attribute__((ext_vector_type(8))) short bf16x8;
typedef __attribute__((ext_vector_type(4))) float f32x4;
typedef unsigned short u16;

// ---- workspace offsets (u16 units) ----
#define XC 3200                 // u16 per x cell (10*10*32)
#define HC2 7168                // u16 per h1 cell (2 halves x 3584)
#define XSEG 617600             // 193 * XC   (cell 192 = zero cell, unused)
#define ZSEG_END 639104         // + 3*7168 h1 zero-cell writes (unused)
#define W1OFF 639104            // 165888 bf16: [tap 0..80][nh(2)][1024]
#define W2OFF 804992            // 165888 bf16: [tap 0..80][kh(2)][1024]
#define H1OFF 970880            // 3 periods x 193 cells x 7168
#define H1P 1383424             // per-period stride = 193*7168
#define PREP_N 970880           // end of weight segment
#define OUT_Q 98304             // out-init float4 count (393216 fp32)
#define PREP_TOT (PREP_N + OUT_Q)

#define WAITVM(N) asm volatile("s_waitcnt vmcnt(" #N ")" ::: "memory")
#define SBAR()    asm volatile("s_barrier" ::: "memory")

__device__ __forceinline__ u16 f2bf(float f) {
    unsigned u = __float_as_uint(f);
    unsigned r = u + 0x7fffu + ((u >> 16) & 1u);
    return (u16)(r >> 16);
}
__device__ __forceinline__ float gelu_exact(float v) {
    return 0.5f * v * (1.0f + erff(v * 0.7071067811865476f));
}

// async copy of 1 KB: 64 lanes x 16 B. LDS dest = wave-uniform base + lane*16.
__device__ __forceinline__ void cp1k(const u16* g, u16* l, int lane) {
    __builtin_amdgcn_global_load_lds(
        (const __attribute__((address_space(1))) unsigned int*)(g + lane * 8),
        (__attribute__((address_space(3))) unsigned int*)(l + lane * 8),
        16, 0, 0);
}

// ---- prep: x cells (swizzled) + h1 zero cells + weights + out = x ----
__global__ __launch_bounds__(256) void prep(
    const float* __restrict__ x,
    const float* __restrict__ w1_0, const float* __restrict__ w1_1,
    const float* __restrict__ w2_0, const float* __restrict__ w2_1,
    u16* __restrict__ ws, float* __restrict__ out) {
    int i = blockIdx.x * 256 + threadIdx.x;
    if (i < XSEG) {
        int cellidx = i / XC; int inner = i - cellidx * XC;
        int cellpos = inner >> 5; int low = inner & 31;
        int sc = low >> 3, jj = low & 7;
        int c = ((sc ^ (cellpos & 3)) << 3) + jj;
        int wp = cellpos / 10, hp = cellpos - (cellpos / 10) * 10;
        float v = 0.f;
        if (cellidx < 192 && wp >= 1 && wp <= 8 && hp >= 1 && hp <= 8)
            v = x[(cellidx * 64 + (wp - 1) * 8 + (hp - 1)) * 32 + c];
        ws[i] = f2bf(v);
    } else if (i < ZSEG_END) {
        int j = i - XSEG;                 // legacy zero cells (now unread)
        int per = j / 7168; int off = j - per * 7168;
        ws[H1OFF + per * H1P + 192 * 7168 + off] = 0;
    } else if (i < W2OFF) {
        // w1: [tap][nh][chunkh(128)*8+jj], chunkh = (quad*2+nq)*16+m
        int j = i - W1OFF;
        int tap = j >> 11; int r = j & 2047;
        int nh = r >> 10; int rr = r & 1023;
        int chunkh = rr >> 3, jj = rr & 7;
        int m = chunkh & 15, nq = (chunkh >> 4) & 1, quad = chunkh >> 5;
        int o = nh * 32 + nq * 16 + m, c = quad * 8 + jj;
        float v = 0.5f * w1_1[(o * 32 + c) * 81 + tap];
        if (tap == 40) v += 0.5f * w1_0[o * 32 + c];
        ws[i] = f2bf(v);
    } else if (i < PREP_N) {
        // w2: [tap][kh][chunkh(128)*8+jj], chunkh = (quad*2+nt)*16+m
        int j = i - W2OFF;
        int tap = j >> 11; int r = j & 2047;
        int kh = r >> 10; int rr = r & 1023;
        int chunkh = rr >> 3, jj = rr & 7;
        int m = chunkh & 15, nt = (chunkh >> 4) & 1, quad = chunkh >> 5;
        int o = nt * 16 + m, c = kh * 32 + quad * 8 + jj;
        float v = 0.5f * w2_1[(o * 64 + c) * 81 + tap];
        if (tap == 40) v += 0.5f * w2_0[o * 64 + c];
        ws[i] = f2bf(v);
    } else if (i < PREP_TOT) {
        int j = i - PREP_N;
        ((float4*)out)[j] = ((const float4*)x)[j];
    }
}

// ---- conv1 (C32 -> 32 of C64, nh half), 6 t-sites per block + GELU.
// 12 waves = (ts in 6, mh in 2), M=32 x N=32 per wave, acc[2][2].
// Static act window (in-range slots only); 9-phase weight ring;
// compute skipped (wave-uniform) on out-of-bounds neighbors. ----
template<int P>
__device__ __forceinline__ void conv1_body(
    const u16* __restrict__ xs, const u16* __restrict__ w1b,
    u16* __restrict__ h1, int tpp, int bb, int nh,
    u16* __restrict__ s_a, u16* __restrict__ s_w) {
    constexpr int HB = (P == 2) ? 0 : (P == 3) ? H1P : 2 * H1P;
    constexpr int L = 48 / P;
    constexpr int EXT = P + 1;
    constexpr int NW = 6 + 2 * EXT;      // window cells (12/14/16)
    constexpr int NP = NW * 7;           // staged pieces (in-range only)

    int tid = threadIdx.x;
    int lane = tid & 63, wv = tid >> 6;  // 12 waves
    int m = lane & 15, quad = lane >> 4;
    int ts = wv >> 1, mh = wv & 1;
    int t0 = tpp * 6, t = t0 + ts;
    int l = t / P, q = t - l * P;

    int sp[2];
#pragma unroll
    for (int mtl = 0; mtl < 2; ++mtl) {
        int pos = (mh * 2 + mtl) * 16 + m;
        sp[mtl] = (pos >> 3) * 10 + (pos & 7);
    }

    f32x4 acc[2][2];
#pragma unroll
    for (int mtl = 0; mtl < 2; ++mtl)
#pragma unroll
        for (int nq = 0; nq < 2; ++nq) acc[mtl][nq] = f32x4{0.f, 0.f, 0.f, 0.f};

    // super-chunk sg = taps 9sg..9sg+8 (one (dl,dq) group), nh half:
    // 18 pieces of 512, 2/wave (k>=18 dup piece 17: same src+dst, benign)
    auto stageS = [&](int sg) {
        const u16* src = w1b + nh * 1024;
        u16* dst = s_w + (sg & 1) * 9216;
#pragma unroll
        for (int i = 0; i < 2; ++i) {
            int k = wv * 2 + i; if (k >= 18) k = 17;
            cp1k(src + (sg * 9 + (k >> 1)) * 2048 + (k & 1) * 512,
                 dst + k * 512, lane);
        }
    };

    // prologue: stage in-range act window slots (slot si <-> t' = t0-EXT+si)
    for (int p = wv; p < NP; p += 12) {
        int si = p / 7, pc = p - si * 7;
        int tt = t0 - EXT + si;
        if ((unsigned)tt < 48u)
            cp1k(xs + (bb * 48 + tt) * XC + pc * 512,
                 s_a + si * 3584 + pc * 512, lane);
    }
    stageS(0);
    WAITVM(0); SBAR();

#pragma unroll 1
    for (int g = 0; g < 9; ++g) {
        // issue S(g+1) into slot (g+1)&1 (last read by compute(g-1); the
        // trailing SBAR of phase g-1 guarantees all waves finished it).
        if (g < 8) stageS(g + 1);

        int dl = g / 3, dq = g - dl * 3;
        int lq = l + dl - 1, qq = q + dq - 1;
        bool valid = ((unsigned)lq < (unsigned)L) &&
                     ((unsigned)qq < (unsigned)P);
        if (valid) {                     // wave-uniform; zero-adds skipped
            int si = ts + dl * P + dq;
            const u16* ba = s_a + si * 3584;
            const u16* bw = s_w + (g & 1) * 9216;
#pragma unroll
            for (int dw = 0; dw < 3; ++dw)
#pragma unroll
                for (int j = 0; j < 3; ++j) {
                    const u16* tw = bw + (dw * 3 + j) * 1024;
                    bf16x8 wf0 = *(const bf16x8*)(tw +
                        (((quad * 2 + 0) * 16 + m) << 3));
                    bf16x8 wf1 = *(const bf16x8*)(tw +
                        (((quad * 2 + 1) * 16 + m) << 3));
#pragma unroll
                    for (int mtl = 0; mtl < 2; ++mtl) {
                        int cellpos = sp[mtl] + dw * 10 + j;
                        bf16x8 af = *(const bf16x8*)(ba + cellpos * 32 +
                            ((quad ^ (cellpos & 3)) << 3));
                        acc[mtl][0] = __builtin_amdgcn_mfma_f32_16x16x32_bf16(
                            af, wf0, acc[mtl][0], 0, 0, 0);
                        acc[mtl][1] = __builtin_amdgcn_mfma_f32_16x16x32_bf16(
                            af, wf1, acc[mtl][1], 0, 0, 0);
                    }
                }
        }
        if (g < 8) { WAITVM(0); SBAR(); }
    }

    // epilogue: GELU -> bf16 -> swizzled half-cell interior
    u16* hh = h1 + HB + (bb * 48 + t) * HC2 + nh * 3584;
#pragma unroll
    for (int mtl = 0; mtl < 2; ++mtl)
#pragma unroll
        for (int r = 0; r < 4; ++r) {
            int pos = (mh * 2 + mtl) * 16 + quad * 4 + r;
            int cellpos = ((pos >> 3) + 1) * 10 + (pos & 7) + 1;
#pragma unroll
            for (int nq = 0; nq < 2; ++nq) {
                int ol = nq * 16 + m;
                hh[cellpos * 32 + (((ol >> 3) ^ (cellpos & 3)) << 3) + (ol & 7)] =
                    f2bf(gelu_exact(acc[mtl][nq][r]));
            }
        }
    // zero the 36 border cellpos of all 6 t half-cells (unique writer)
#pragma unroll
    for (int it = 0; it < 5; ++it) {
        int k = it * 768 + tid;                    // 6*576 = 3456 entries
        if (k < 3456) {
            int tc = k / 576; int rr = k - tc * 576;
            int bp = rr >> 4, u = rr & 15;
            int cp;
            if (bp < 10) cp = bp;
            else if (bp < 20) cp = 90 + (bp - 10);
            else if (bp < 28) cp = (bp - 19) * 10;
            else cp = (bp - 27) * 10 + 9;
            unsigned int* h32 = (unsigned int*)(h1 + HB +
                (bb * 48 + t0 + tc) * HC2 + nh * 3584);
            h32[cp * 16 + u] = 0;
        }
    }
}

__global__ __launch_bounds__(768) void conv1_k(
    const u16* __restrict__ ws_x, const u16* __restrict__ ws_w1,
    u16* __restrict__ ws_h1) {
    __shared__ __align__(16) u16 s_a[16 * 3584];   // 112 KB act window
    __shared__ __align__(16) u16 s_w[2 * 9216];    // 36 KB super-chunk ring
    int g = blockIdx.x;
    int jid = (g & 7) * 24 + (g >> 3);             // XCD-chunked, 192 = 8*24
    int per = jid / 64; int rem = jid - per * 64;
    int bb = rem / 16; int r2 = rem - bb * 16;
    int tpp = r2 >> 1, nh = r2 & 1;
    if (per == 0)      conv1_body<2>(ws_x, ws_w1, ws_h1, tpp, bb, nh, s_a, s_w);
    else if (per == 1) conv1_body<3>(ws_x, ws_w1, ws_h1, tpp, bb, nh, s_a, s_w);
    else               conv1_body<4>(ws_x, ws_w1, ws_h1, tpp, bb, nh, s_a, s_w);
}

// ---- conv2 (32 of C64 -> C32 partial, kh half), 6 t-sites per block.
// Same 9-phase skip structure; epilogue atomicAdds acc/3 into out. ----
template<int P>
__device__ __forceinline__ void conv2_body(
    const u16* __restrict__ h1, const u16* __restrict__ w2b,
    float* __restrict__ out, int tpp, int bb, int kh,
    u16* __restrict__ s_a, u16* __restrict__ s_w) {
    constexpr int HB = (P == 2) ? 0 : (P == 3) ? H1P : 2 * H1P;
    constexpr int L = 48 / P;
    constexpr int EXT = P + 1;
    constexpr int NW = 6 + 2 * EXT;
    constexpr int NP = NW * 7;

    int tid = threadIdx.x;
    int lane = tid & 63, wv = tid >> 6;
    int m = lane & 15, quad = lane >> 4;
    int ts = wv >> 1, mh = wv & 1;
    int t0 = tpp * 6, t = t0 + ts;
    int l = t / P, q = t - l * P;
    const u16* hb = h1 + HB;

    int sp[2];
#pragma unroll
    for (int mtl = 0; mtl < 2; ++mtl) {
        int pos = (mh * 2 + mtl) * 16 + m;
        sp[mtl] = (pos >> 3) * 10 + (pos & 7);
    }

    f32x4 acc[2][2];
#pragma unroll
    for (int mtl = 0; mtl < 2; ++mtl)
#pragma unroll
        for (int nt = 0; nt < 2; ++nt) acc[mtl][nt] = f32x4{0.f, 0.f, 0.f, 0.f};

    auto stageS = [&](int sg) {
        const u16* src = w2b + kh * 1024;
        u16* dst = s_w + (sg & 1) * 9216;
#pragma unroll
        for (int i = 0; i < 2; ++i) {
            int k = wv * 2 + i; if (k >= 18) k = 17;
            cp1k(src + (sg * 9 + (k >> 1)) * 2048 + (k & 1) * 512,
                 dst + k * 512, lane);
        }
    };

    for (int p = wv; p < NP; p += 12) {
        int si = p / 7, pc = p - si * 7;
        int tt = t0 - EXT + si;
        if ((unsigned)tt < 48u)
            cp1k(hb + (bb * 48 + tt) * HC2 + kh * 3584 + pc * 512,
                 s_a + si * 3584 + pc * 512, lane);
    }
    stageS(0);
    WAITVM(0); SBAR();

#pragma unroll 1
    for (int g = 0; g < 9; ++g) {
        if (g < 8) stageS(g + 1);

        int dl = g / 3, dq = g - dl * 3;
        int lq = l + dl - 1, qq = q + dq - 1;
        bool valid = ((unsigned)lq < (unsigned)L) &&
                     ((unsigned)qq < (unsigned)P);
        if (valid) {
            int si = ts + dl * P + dq;
            const u16* ba = s_a + si * 3584;
            const u16* bw = s_w + (g & 1) * 9216;
#pragma unroll
            for (int dw = 0; dw < 3; ++dw)
#pragma unroll
                for (int j = 0; j < 3; ++j) {
                    const u16* tw = bw + (dw * 3 + j) * 1024;
                    bf16x8 wf0 = *(const bf16x8*)(tw +
                        (((quad * 2 + 0) * 16 + m) << 3));
                    bf16x8 wf1 = *(const bf16x8*)(tw +
                        (((quad * 2 + 1) * 16 + m) << 3));
#pragma unroll
                    for (int mtl = 0; mtl < 2; ++mtl) {
                        int cellpos = sp[mtl] + dw * 10 + j;
                        bf16x8 af = *(const bf16x8*)(ba + cellpos * 32 +
                            ((quad ^ (cellpos & 3)) << 3));
                        acc[mtl][0] = __builtin_amdgcn_mfma_f32_16x16x32_bf16(
                            af, wf0, acc[mtl][0], 0, 0, 0);
                        acc[mtl][1] = __builtin_amdgcn_mfma_f32_16x16x32_bf16(
                            af, wf1, acc[mtl][1], 0, 0, 0);
                    }
                }
        }
        if (g < 8) { WAITVM(0); SBAR(); }
    }

    // epilogue: out += acc/3 (softmax(ones) weights); out pre-filled with x
    float* orow = out + (bb * 48 + t) * 2048;
    const float s = 1.0f / 3.0f;
#pragma unroll
    for (int mtl = 0; mtl < 2; ++mtl)
#pragma unroll
        for (int nt = 0; nt < 2; ++nt)
#pragma unroll
            for (int r = 0; r < 4; ++r) {
                int pos = (mh * 2 + mtl) * 16 + quad * 4 + r;
                atomicAdd(&orow[pos * 32 + nt * 16 + m], acc[mtl][nt][r] * s);
            }
}

__global__ __launch_bounds__(768) void conv2_k(
    const u16* __restrict__ ws_h1, const u16* __restrict__ ws_w2,
    float* __restrict__ out) {
    __shared__ __align__(16) u16 s_a[16 * 3584];   // 112 KB act window
    __shared__ __align__(16) u16 s_w[2 * 9216];    // 36 KB super-chunk ring
    int g = blockIdx.x;
    int jid = (g & 7) * 24 + (g >> 3);             // same XCD mapping as conv1
    int per = jid / 64; int rem = jid - per * 64;
    int bb = rem / 16; int r2 = rem - bb * 16;
    int tpp = r2 >> 1, kh = r2 & 1;
    if (per == 0)      conv2_body<2>(ws_h1, ws_w2, out, tpp, bb, kh, s_a, s_w);
    else if (per == 1) conv2_body<3>(ws_h1, ws_w2, out, tpp, bb, kh, s_a, s_w);
    else               conv2_body<4>(ws_h1, ws_w2, out, tpp, bb, kh, s_a, s_w);
}

extern "C" void kernel_launch(void* const* d_in, const int* in_sizes, int n_in,
                              void* d_out, int out_size, void* d_ws, size_t ws_size,
                              hipStream_t stream) {
    const float* x    = (const float*)d_in[0];
    const float* w1_0 = (const float*)d_in[1];
    const float* w1_1 = (const float*)d_in[2];
    const float* w2_0 = (const float*)d_in[3];
    const float* w2_1 = (const float*)d_in[4];
    float* out = (float*)d_out;

    u16* ws = (u16*)d_ws;
    u16* ws_x  = ws;                 // 193 cells (192 real + zero)
    u16* ws_w1 = ws + W1OFF;
    u16* ws_w2 = ws + W2OFF;
    u16* ws_h1 = ws + H1OFF;         // 3 x 193 cells x 7168

    prep<<<(PREP_TOT + 255) / 256, 256, 0, stream>>>(
        x, w1_0, w1_1, w2_0, w2_1, ws, out);
    conv1_k<<<192, 768, 0, stream>>>(ws_x, ws_w1, ws_h1);
    conv2_k<<<192, 768, 0, stream>>>(ws_h1, ws_w2, out);
}

// Round 10
// 106.242 us; speedup vs baseline: 1.2169x; 1.0292x over previous
//
#include <hip/hip_runtime.h>
#include <math.h>

// B=4, T=48, W=8, H=8, C=32; d_ff=64; periods {2,3,4}. T%P==0 always.
// (1x1 + 3^4)/2 inception folded into one 81-tap conv (center tap 40).
// R24 = R23 (12-wave blocks, static act window, 9-phase weight ring,
// skip-invalid compute) + GRID REBALANCE 192 -> 240 blocks:
//   * R23 left 64/256 CUs idle (1 blk/CU at 148 KB). Split each
//     (per,bb,half) group's 48 t into 8x5-site + 2x4-site blocks -> 240
//     blocks, critical block 10 working waves (vs 12) -> per-CU per-phase
//     LDS reads 432 -> 360 (0.83x).
//   * sites runtime (5 or 4); waves with ts>=sites idle through compute but
//     still stage weights + hit every WAITVM/SBAR -> protocol unchanged.
//   * window NW = sites+2(P+1) <= 15 slots; LDS 105+36 = 141 KB.
//   * All layouts/ladders/epilogues verbatim from R23 (bit-identical math).

typedef __attribute__((ext_vector_type(8))) short bf16x8;
typedef __attribute__((ext_vector_type(4))) float f32x4;
typedef unsigned short u16;

// ---- workspace offsets (u16 units) ----
#define XC 3200                 // u16 per x cell (10*10*32)
#define HC2 7168                // u16 per h1 cell (2 halves x 3584)
#define XSEG 617600             // 193 * XC   (cell 192 = zero cell, unused)
#define ZSEG_END 639104         // + 3*7168 h1 zero-cell writes (unused)
#define W1OFF 639104            // 165888 bf16: [tap 0..80][nh(2)][1024]
#define W2OFF 804992            // 165888 bf16: [tap 0..80][kh(2)][1024]
#define H1OFF 970880            // 3 periods x 193 cells x 7168
#define H1P 1383424             // per-period stride = 193*7168
#define PREP_N 970880           // end of weight segment
#define OUT_Q 98304             // out-init float4 count (393216 fp32)
#define PREP_TOT (PREP_N + OUT_Q)

#define WAITVM(N) asm volatile("s_waitcnt vmcnt(" #N ")" ::: "memory")
#define SBAR()    asm volatile("s_barrier" ::: "memory")

__device__ __forceinline__ u16 f2bf(float f) {
    unsigned u = __float_as_uint(f);
    unsigned r = u + 0x7fffu + ((u >> 16) & 1u);
    return (u16)(r >> 16);
}
__device__ __forceinline__ float gelu_exact(float v) {
    return 0.5f * v * (1.0f + erff(v * 0.7071067811865476f));
}

// async copy of 1 KB: 64 lanes x 16 B. LDS dest = wave-uniform base + lane*16.
__device__ __forceinline__ void cp1k(const u16* g, u16* l, int lane) {
    __builtin_amdgcn_global_load_lds(
        (const __attribute__((address_space(1))) unsigned int*)(g + lane * 8),
        (__attribute__((address_space(3))) unsigned int*)(l + lane * 8),
        16, 0, 0);
}

// ---- prep: x cells (swizzled) + h1 zero cells + weights + out = x ----
__global__ __launch_bounds__(256) void prep(
    const float* __restrict__ x,
    const float* __restrict__ w1_0, const float* __restrict__ w1_1,
    const float* __restrict__ w2_0, const float* __restrict__ w2_1,
    u16* __restrict__ ws, float* __restrict__ out) {
    int i = blockIdx.x * 256 + threadIdx.x;
    if (i < XSEG) {
        int cellidx = i / XC; int inner = i - cellidx * XC;
        int cellpos = inner >> 5; int low = inner & 31;
        int sc = low >> 3, jj = low & 7;
        int c = ((sc ^ (cellpos & 3)) << 3) + jj;
        int wp = cellpos / 10, hp = cellpos - (cellpos / 10) * 10;
        float v = 0.f;
        if (cellidx < 192 && wp >= 1 && wp <= 8 && hp >= 1 && hp <= 8)
            v = x[(cellidx * 64 + (wp - 1) * 8 + (hp - 1)) * 32 + c];
        ws[i] = f2bf(v);
    } else if (i < ZSEG_END) {
        int j = i - XSEG;                 // legacy zero cells (now unread)
        int per = j / 7168; int off = j - per * 7168;
        ws[H1OFF + per * H1P + 192 * 7168 + off] = 0;
    } else if (i < W2OFF) {
        // w1: [tap][nh][chunkh(128)*8+jj], chunkh = (quad*2+nq)*16+m
        int j = i - W1OFF;
        int tap = j >> 11; int r = j & 2047;
        int nh = r >> 10; int rr = r & 1023;
        int chunkh = rr >> 3, jj = rr & 7;
        int m = chunkh & 15, nq = (chunkh >> 4) & 1, quad = chunkh >> 5;
        int o = nh * 32 + nq * 16 + m, c = quad * 8 + jj;
        float v = 0.5f * w1_1[(o * 32 + c) * 81 + tap];
        if (tap == 40) v += 0.5f * w1_0[o * 32 + c];
        ws[i] = f2bf(v);
    } else if (i < PREP_N) {
        // w2: [tap][kh][chunkh(128)*8+jj], chunkh = (quad*2+nt)*16+m
        int j = i - W2OFF;
        int tap = j >> 11; int r = j & 2047;
        int kh = r >> 10; int rr = r & 1023;
        int chunkh = rr >> 3, jj = rr & 7;
        int m = chunkh & 15, nt = (chunkh >> 4) & 1, quad = chunkh >> 5;
        int o = nt * 16 + m, c = kh * 32 + quad * 8 + jj;
        float v = 0.5f * w2_1[(o * 64 + c) * 81 + tap];
        if (tap == 40) v += 0.5f * w2_0[o * 64 + c];
        ws[i] = f2bf(v);
    } else if (i < PREP_TOT) {
        int j = i - PREP_N;
        ((float4*)out)[j] = ((const float4*)x)[j];
    }
}

// decode jid -> (per, bb, half, t0, sites): 24 groups x 10 blocks
__device__ __forceinline__ void decode240(int jid, int& per, int& bb,
                                          int& half, int& t0, int& sites) {
    int group = jid / 10, b = jid - group * 10;
    per = group >> 3; int rem = group & 7;
    bb = rem >> 1; half = rem & 1;
    if (b < 8) { t0 = 5 * b;            sites = 5; }
    else       { t0 = 40 + 4 * (b - 8); sites = 4; }
}

// ---- conv1 (C32 -> 32 of C64, nh half), 4-5 t-sites per block + GELU.
// 12 waves = (ts, mh); ts >= sites waves idle through compute but keep the
// staging/barrier protocol. Static act window; 9-phase weight ring;
// compute skipped (wave-uniform) on out-of-bounds neighbors. ----
template<int P>
__device__ __forceinline__ void conv1_body(
    const u16* __restrict__ xs, const u16* __restrict__ w1b,
    u16* __restrict__ h1, int t0, int sites, int bb, int nh,
    u16* __restrict__ s_a, u16* __restrict__ s_w) {
    constexpr int HB = (P == 2) ? 0 : (P == 3) ? H1P : 2 * H1P;
    constexpr int L = 48 / P;
    constexpr int EXT = P + 1;
    const int NW = sites + 2 * EXT;      // window cells (<=15)
    const int NP = NW * 7;               // staged pieces (in-range only)

    int tid = threadIdx.x;
    int lane = tid & 63, wv = tid >> 6;  // 12 waves
    int m = lane & 15, quad = lane >> 4;
    int ts = wv >> 1, mh = wv & 1;
    int t = t0 + ts;
    int l = t / P, q = t - l * P;
    bool active = ts < sites;

    int sp[2];
#pragma unroll
    for (int mtl = 0; mtl < 2; ++mtl) {
        int pos = (mh * 2 + mtl) * 16 + m;
        sp[mtl] = (pos >> 3) * 10 + (pos & 7);
    }

    f32x4 acc[2][2];
#pragma unroll
    for (int mtl = 0; mtl < 2; ++mtl)
#pragma unroll
        for (int nq = 0; nq < 2; ++nq) acc[mtl][nq] = f32x4{0.f, 0.f, 0.f, 0.f};

    // super-chunk sg = taps 9sg..9sg+8 (one (dl,dq) group), nh half:
    // 18 pieces of 512, 2/wave (k>=18 dup piece 17: same src+dst, benign)
    auto stageS = [&](int sg) {
        const u16* src = w1b + nh * 1024;
        u16* dst = s_w + (sg & 1) * 9216;
#pragma unroll
        for (int i = 0; i < 2; ++i) {
            int k = wv * 2 + i; if (k >= 18) k = 17;
            cp1k(src + (sg * 9 + (k >> 1)) * 2048 + (k & 1) * 512,
                 dst + k * 512, lane);
        }
    };

    // prologue: stage in-range act window slots (slot si <-> t' = t0-EXT+si)
    for (int p = wv; p < NP; p += 12) {
        int si = p / 7, pc = p - si * 7;
        int tt = t0 - EXT + si;
        if ((unsigned)tt < 48u)
            cp1k(xs + (bb * 48 + tt) * XC + pc * 512,
                 s_a + si * 3584 + pc * 512, lane);
    }
    stageS(0);
    WAITVM(0); SBAR();

#pragma unroll 1
    for (int g = 0; g < 9; ++g) {
        // issue S(g+1) into slot (g+1)&1 (last read by compute(g-1); the
        // trailing SBAR of phase g-1 guarantees all waves finished it).
        if (g < 8) stageS(g + 1);

        int dl = g / 3, dq = g - dl * 3;
        int lq = l + dl - 1, qq = q + dq - 1;
        bool valid = active && ((unsigned)lq < (unsigned)L) &&
                     ((unsigned)qq < (unsigned)P);
        if (valid) {                     // wave-uniform; zero-adds skipped
            int si = ts + dl * P + dq;
            const u16* ba = s_a + si * 3584;
            const u16* bw = s_w + (g & 1) * 9216;
#pragma unroll
            for (int dw = 0; dw < 3; ++dw)
#pragma unroll
                for (int j = 0; j < 3; ++j) {
                    const u16* tw = bw + (dw * 3 + j) * 1024;
                    bf16x8 wf0 = *(const bf16x8*)(tw +
                        (((quad * 2 + 0) * 16 + m) << 3));
                    bf16x8 wf1 = *(const bf16x8*)(tw +
                        (((quad * 2 + 1) * 16 + m) << 3));
#pragma unroll
                    for (int mtl = 0; mtl < 2; ++mtl) {
                        int cellpos = sp[mtl] + dw * 10 + j;
                        bf16x8 af = *(const bf16x8*)(ba + cellpos * 32 +
                            ((quad ^ (cellpos & 3)) << 3));
                        acc[mtl][0] = __builtin_amdgcn_mfma_f32_16x16x32_bf16(
                            af, wf0, acc[mtl][0], 0, 0, 0);
                        acc[mtl][1] = __builtin_amdgcn_mfma_f32_16x16x32_bf16(
                            af, wf1, acc[mtl][1], 0, 0, 0);
                    }
                }
        }
        if (g < 8) { WAITVM(0); SBAR(); }
    }

    // epilogue: GELU -> bf16 -> swizzled half-cell interior
    if (active) {
        u16* hh = h1 + HB + (bb * 48 + t) * HC2 + nh * 3584;
#pragma unroll
        for (int mtl = 0; mtl < 2; ++mtl)
#pragma unroll
            for (int r = 0; r < 4; ++r) {
                int pos = (mh * 2 + mtl) * 16 + quad * 4 + r;
                int cellpos = ((pos >> 3) + 1) * 10 + (pos & 7) + 1;
#pragma unroll
                for (int nq = 0; nq < 2; ++nq) {
                    int ol = nq * 16 + m;
                    hh[cellpos * 32 + (((ol >> 3) ^ (cellpos & 3)) << 3) +
                       (ol & 7)] = f2bf(gelu_exact(acc[mtl][nq][r]));
                }
            }
    }
    // zero the 36 border cellpos of all covered t half-cells
#pragma unroll
    for (int it = 0; it < 5; ++it) {
        int k = it * 768 + tid;                    // sites*576 <= 2880
        if (k < sites * 576) {
            int tc = k / 576; int rr = k - tc * 576;
            int bp = rr >> 4, u = rr & 15;
            int cp;
            if (bp < 10) cp = bp;
            else if (bp < 20) cp = 90 + (bp - 10);
            else if (bp < 28) cp = (bp - 19) * 10;
            else cp = (bp - 27) * 10 + 9;
            unsigned int* h32 = (unsigned int*)(h1 + HB +
                (bb * 48 + t0 + tc) * HC2 + nh * 3584);
            h32[cp * 16 + u] = 0;
        }
    }
}

__global__ __launch_bounds__(768) void conv1_k(
    const u16* __restrict__ ws_x, const u16* __restrict__ ws_w1,
    u16* __restrict__ ws_h1) {
    __shared__ __align__(16) u16 s_a[15 * 3584];   // 105 KB act window
    __shared__ __align__(16) u16 s_w[2 * 9216];    // 36 KB super-chunk ring
    int g = blockIdx.x;
    int jid = (g & 7) * 30 + (g >> 3);             // XCD-chunked, 240 = 8*30
    int per, bb, nh, t0, sites;
    decode240(jid, per, bb, nh, t0, sites);
    if (per == 0)
        conv1_body<2>(ws_x, ws_w1, ws_h1, t0, sites, bb, nh, s_a, s_w);
    else if (per == 1)
        conv1_body<3>(ws_x, ws_w1, ws_h1, t0, sites, bb, nh, s_a, s_w);
    else
        conv1_body<4>(ws_x, ws_w1, ws_h1, t0, sites, bb, nh, s_a, s_w);
}

// ---- conv2 (32 of C64 -> C32 partial, kh half), 4-5 t-sites per block.
// Same 9-phase skip structure; epilogue atomicAdds acc/3 into out. ----
template<int P>
__device__ __forceinline__ void conv2_body(
    const u16* __restrict__ h1, const u16* __restrict__ w2b,
    float* __restrict__ out, int t0, int sites, int bb, int kh,
    u16* __restrict__ s_a, u16* __restrict__ s_w) {
    constexpr int HB = (P == 2) ? 0 : (P == 3) ? H1P : 2 * H1P;
    constexpr int L = 48 / P;
    constexpr int EXT = P + 1;
    const int NW = sites + 2 * EXT;
    const int NP = NW * 7;

    int tid = threadIdx.x;
    int lane = tid & 63, wv = tid >> 6;
    int m = lane & 15, quad = lane >> 4;
    int ts = wv >> 1, mh = wv & 1;
    int t = t0 + ts;
    int l = t / P, q = t - l * P;
    const u16* hb = h1 + HB;
    bool active = ts < sites;

    int sp[2];
#pragma unroll
    for (int mtl = 0; mtl < 2; ++mtl) {
        int pos = (mh * 2 + mtl) * 16 + m;
        sp[mtl] = (pos >> 3) * 10 + (pos & 7);
    }

    f32x4 acc[2][2];
#pragma unroll
    for (int mtl = 0; mtl < 2; ++mtl)
#pragma unroll
        for (int nt = 0; nt < 2; ++nt) acc[mtl][nt] = f32x4{0.f, 0.f, 0.f, 0.f};

    auto stageS = [&](int sg) {
        const u16* src = w2b + kh * 1024;
        u16* dst = s_w + (sg & 1) * 9216;
#pragma unroll
        for (int i = 0; i < 2; ++i) {
            int k = wv * 2 + i; if (k >= 18) k = 17;
            cp1k(src + (sg * 9 + (k >> 1)) * 2048 + (k & 1) * 512,
                 dst + k * 512, lane);
        }
    };

    for (int p = wv; p < NP; p += 12) {
        int si = p / 7, pc = p - si * 7;
        int tt = t0 - EXT + si;
        if ((unsigned)tt < 48u)
            cp1k(hb + (bb * 48 + tt) * HC2 + kh * 3584 + pc * 512,
                 s_a + si * 3584 + pc * 512, lane);
    }
    stageS(0);
    WAITVM(0); SBAR();

#pragma unroll 1
    for (int g = 0; g < 9; ++g) {
        if (g < 8) stageS(g + 1);

        int dl = g / 3, dq = g - dl * 3;
        int lq = l + dl - 1, qq = q + dq - 1;
        bool valid = active && ((unsigned)lq < (unsigned)L) &&
                     ((unsigned)qq < (unsigned)P);
        if (valid) {
            int si = ts + dl * P + dq;
            const u16* ba = s_a + si * 3584;
            const u16* bw = s_w + (g & 1) * 9216;
#pragma unroll
            for (int dw = 0; dw < 3; ++dw)
#pragma unroll
                for (int j = 0; j < 3; ++j) {
                    const u16* tw = bw + (dw * 3 + j) * 1024;
                    bf16x8 wf0 = *(const bf16x8*)(tw +
                        (((quad * 2 + 0) * 16 + m) << 3));
                    bf16x8 wf1 = *(const bf16x8*)(tw +
                        (((quad * 2 + 1) * 16 + m) << 3));
#pragma unroll
                    for (int mtl = 0; mtl < 2; ++mtl) {
                        int cellpos = sp[mtl] + dw * 10 + j;
                        bf16x8 af = *(const bf16x8*)(ba + cellpos * 32 +
                            ((quad ^ (cellpos & 3)) << 3));
                        acc[mtl][0] = __builtin_amdgcn_mfma_f32_16x16x32_bf16(
                            af, wf0, acc[mtl][0], 0, 0, 0);
                        acc[mtl][1] = __builtin_amdgcn_mfma_f32_16x16x32_bf16(
                            af, wf1, acc[mtl][1], 0, 0, 0);
                    }
                }
        }
        if (g < 8) { WAITVM(0); SBAR(); }
    }

    // epilogue: out += acc/3 (softmax(ones) weights); out pre-filled with x
    if (active) {
        float* orow = out + (bb * 48 + t) * 2048;
        const float s = 1.0f / 3.0f;
#pragma unroll
        for (int mtl = 0; mtl < 2; ++mtl)
#pragma unroll
            for (int nt = 0; nt < 2; ++nt)
#pragma unroll
                for (int r = 0; r < 4; ++r) {
                    int pos = (mh * 2 + mtl) * 16 + quad * 4 + r;
                    atomicAdd(&orow[pos * 32 + nt * 16 + m],
                              acc[mtl][nt][r] * s);
                }
    }
}

__global__ __launch_bounds__(768) void conv2_k(
    const u16* __restrict__ ws_h1, const u16* __restrict__ ws_w2,
    float* __restrict__ out) {
    __shared__ __align__(16) u16 s_a[15 * 3584];   // 105 KB act window
    __shared__ __align__(16) u16 s_w[2 * 9216];    // 36 KB super-chunk ring
    int g = blockIdx.x;
    int jid = (g & 7) * 30 + (g >> 3);             // same XCD mapping
    int per, bb, kh, t0, sites;
    decode240(jid, per, bb, kh, t0, sites);
    if (per == 0)
        conv2_body<2>(ws_h1, ws_w2, out, t0, sites, bb, kh, s_a, s_w);
    else if (per == 1)
        conv2_body<3>(ws_h1, ws_w2, out, t0, sites, bb, kh, s_a, s_w);
    else
        conv2_body<4>(ws_h1, ws_w2, out, t0, sites, bb, kh, s_a, s_w);
}

extern "C" void kernel_launch(void* const* d_in, const int* in_sizes, int n_in,
                              void* d_out, int out_size, void* d_ws, size_t ws_size,
                              hipStream_t stream) {
    const float* x    = (const float*)d_in[0];
    const float* w1_0 = (const float*)d_in[1];
    const float* w1_1 = (const float*)d_in[2];
    const float* w2_0 = (const float*)d_in[3];
    const float* w2_1 = (const float*)d_in[4];
    float* out = (float*)d_out;

    u16* ws = (u16*)d_ws;
    u16* ws_x  = ws;                 // 193 cells (192 real + zero)
    u16* ws_w1 = ws + W1OFF;
    u16* ws_w2 = ws + W2OFF;
    u16* ws_h1 = ws + H1OFF;         // 3 x 193 cells x 7168

    prep<<<(PREP_TOT + 255) / 256, 256, 0, stream>>>(
        x, w1_0, w1_1, w2_0, w2_1, ws, out);
    conv1_k<<<240, 768, 0, stream>>>(ws_x, ws_w1, ws_h1);
    conv2_k<<<240, 768, 0, stream>>>(ws_h1, ws_w2, out);
}